// Round 1
// baseline (178.370 us; speedup 1.0000x reference)
//
#include <hip/hip_runtime.h>

// Problem constants (from reference)
#define N_GRAPHS  4096
#define NPG       256      // nodes per graph (contiguous batch segments)
#define F_IN      16
#define HID       32
#define LOG2E     1.4426950408889634f

// d_ws float layout:
//  [0..255]   : frag Z — 64 lanes x 16B f16, mfma_f32_32x32x16_f16 B layout,
//               lane l: col=l&31, k=(l>>5)*8+j. Pre-scaled by log2e.
//  [256..511] : frag H — same layout, pre-scaled by 2*log2e (raw exp2 use).
//  [512..543] : bz * log2e
//  [544..575] : bh * 2*log2e
//  [576..607] : W_lin
//  [608]      : b_lin
#define WS_FLOATS 609

typedef _Float16 half8  __attribute__((ext_vector_type(8)));   // 4 VGPR MFMA A/B
typedef float    f32x16 __attribute__((ext_vector_type(16)));  // MFMA C/D 32x32

#if __has_builtin(__builtin_amdgcn_exp2f)
#define EXP2(x) __builtin_amdgcn_exp2f(x)
#else
#define EXP2(x) exp2f(x)
#endif

union FragU { uint4 u; half8 h; };

// B fragment for lane l of frag f. W element [r][c] at r*32+c; second
// diffusion-direction copy at +1536 (W is (2,1,48,32), K=1 => sum both).
// NOTE: A is packed with the SAME lane->k map, so the contraction pairs
// x[k] with W[k] regardless of the true within-lane k order (layout-robust).
__device__ __forceinline__ uint4 make_frag32(int f, int l,
    const float* __restrict__ Wz, const float* __restrict__ Wh)
{
    const int col = l & 31, p = l >> 5;
    const float s = (f == 0) ? LOG2E : 2.0f * LOG2E;
    const float* W = (f == 0) ? Wz : Wh;
    FragU u;
#pragma unroll
    for (int j = 0; j < 8; ++j) {
        const int k = p * 8 + j;
        u.h[j] = (_Float16)((W[k * 32 + col] + W[1536 + k * 32 + col]) * s);
    }
    return u.u;
}

__global__ __launch_bounds__(256) void prep_kernel(
    const float* __restrict__ Wz, const float* __restrict__ bz,
    const float* __restrict__ Wh, const float* __restrict__ bh,
    const float* __restrict__ Wlin, const float* __restrict__ blin,
    float* __restrict__ w)
{
    const int t = threadIdx.x;                       // 256 threads, 1 block
    if (t < 128) ((uint4*)w)[t] = make_frag32(t >> 6, t & 63, Wz, Wh);
    if (t < HID) {
        w[512 + t] = bz[t] * LOG2E;
        w[544 + t] = bh[t] * (2.0f * LOG2E);
        w[576 + t] = Wlin[t];
    }
    if (t == 0) w[608] = blin[0];
}

// One (node, col) activation: omz*tanh merged into a single rcp.
// v = (e2-1) / ((1+e1)*(e2+1)); clamp keeps e2 finite (avoids inf*0 NaN).
__device__ __forceinline__ float gate_term(float az, float ah, float wl, float osum)
{
    const float e1 = EXP2(az);
    const float e2 = EXP2(fminf(ah, 126.0f));
    const float r  = __builtin_amdgcn_rcpf((1.0f + e1) * (e2 + 1.0f));
    float v = (e2 - 1.0f) * r;
    v = v > 0.0f ? v : 0.0f;                 // relu (omz>0, sign is tanh's)
    return fmaf(v, wl, osum);
}

// One 32-node tile: hi/lo f32->f16 split via two chained MFMAs per gate.
// A layout: lane l holds node (tile + (l&31)), features (l>>5)*8 .. +8 —
// 64 lanes x 8 = exactly 32 nodes x 16 features, zero duplication.
// C/D layout (HW-verified): col = lane&31, rows bijective over 0..31.
__device__ __forceinline__ float tile32(float4 c0, float4 c1,
    half8 Bz, half8 Bh, float bzl, float bhl, float wll, float osum)
{
    const float xf[8] = { c0.x, c0.y, c0.z, c0.w, c1.x, c1.y, c1.z, c1.w };
    half8 Ah, Al;
#pragma unroll
    for (int j = 0; j < 8; ++j) {
        const _Float16 h = (_Float16)xf[j];            // hi
        Ah[j] = h;
        Al[j] = (_Float16)(xf[j] - (float)h);          // exact residual
    }
    f32x16 accZ, accH;
#pragma unroll
    for (int i = 0; i < 16; ++i) { accZ[i] = bzl; accH[i] = bhl; }
    accZ = __builtin_amdgcn_mfma_f32_32x32x16_f16(Ah, Bz, accZ, 0, 0, 0);
    accH = __builtin_amdgcn_mfma_f32_32x32x16_f16(Ah, Bh, accH, 0, 0, 0);
    accZ = __builtin_amdgcn_mfma_f32_32x32x16_f16(Al, Bz, accZ, 0, 0, 0);
    accH = __builtin_amdgcn_mfma_f32_32x32x16_f16(Al, Bh, accH, 0, 0, 0);
#pragma unroll
    for (int i = 0; i < 16; ++i)
        osum = gate_term(accZ[i], accH[i], wll, osum);
    return osum;
}

// One block = one graph. Wave wv: nodes [wv*64, wv*64+64) as 2 MFMA tiles of
// 32 nodes. Both tiles' x loaded up-front (4x float4/thread, fully coalesced).
__device__ __forceinline__ void gcn_body(const float* __restrict__ x,
                                         const float* __restrict__ w,
                                         float* __restrict__ out, int g, int t)
{
    const int lane = t & 63, wv = t >> 6;
    const int col = lane & 31, p = lane >> 5;

    // B fragments: 2 coalesced 16B loads, already packed.
    const uint4* bq = (const uint4*)w;
    FragU uz, uh;
    uz.u = bq[lane];
    uh.u = bq[64 + lane];

    const float bzl = w[512 + col];
    const float bhl = w[544 + col];
    const float wll = w[576 + col];

    // Lane (p,col) loads features p*8..+8 of node wv*64 + tile*32 + col.
    const float* xw = x + ((size_t)g * NPG + wv * 64 + col) * F_IN + p * 8;
    const float4 a0 = *(const float4*)(xw);
    const float4 a1 = *(const float4*)(xw + 4);
    const float4 b0 = *(const float4*)(xw + 512);      // +32 nodes
    const float4 b1 = *(const float4*)(xw + 512 + 4);

    float osum = tile32(a0, a1, uz.h, uh.h, bzl, bhl, wll, 0.0f);
    osum       = tile32(b0, b1, uz.h, uh.h, bzl, bhl, wll, osum);

    // Wave butterfly, then 4 partials via LDS.
#pragma unroll
    for (int off = 32; off > 0; off >>= 1)
        osum += __shfl_down(osum, off, 64);
    __shared__ float part[4];
    if (lane == 0) part[wv] = osum;
    __syncthreads();
    if (t == 0)
        out[g] = (part[0] + part[1] + part[2] + part[3]) * (1.0f / (float)NPG)
               + w[608];
}

__global__ __launch_bounds__(256, 5) void gcn_main(
    const float* __restrict__ x, const float* __restrict__ w, float* __restrict__ out)
{
    gcn_body(x, w, out, blockIdx.x, threadIdx.x);
}

// Fallback if ws_size too small: build the same 609-float image in LDS.
__global__ __launch_bounds__(256, 5) void gcn_main_lds(
    const float* __restrict__ x,
    const float* __restrict__ Wz, const float* __restrict__ bz,
    const float* __restrict__ Wh, const float* __restrict__ bh,
    const float* __restrict__ Wlin, const float* __restrict__ blin,
    float* __restrict__ out)
{
    __shared__ __attribute__((aligned(16))) float w[WS_FLOATS];
    const int t = threadIdx.x;
    if (t < 128) ((uint4*)w)[t] = make_frag32(t >> 6, t & 63, Wz, Wh);
    if (t < HID) {
        w[512 + t] = bz[t] * LOG2E;
        w[544 + t] = bh[t] * (2.0f * LOG2E);
        w[576 + t] = Wlin[t];
    }
    if (t == 0) w[608] = blin[0];
    __syncthreads();
    gcn_body(x, w, out, blockIdx.x, t);
}

extern "C" void kernel_launch(void* const* d_in, const int* in_sizes, int n_in,
                              void* d_out, int out_size, void* d_ws, size_t ws_size,
                              hipStream_t stream)
{
    // 0:x 1:edge_index 2:edge_weight 3:batch 4:W_z 5:b_z 6:W_r 7:b_r 8:W_h 9:b_h 10:W_lin 11:b_lin
    const float* x    = (const float*)d_in[0];
    const float* Wz   = (const float*)d_in[4];
    const float* bz   = (const float*)d_in[5];
    const float* Wh   = (const float*)d_in[8];
    const float* bh   = (const float*)d_in[9];
    const float* Wlin = (const float*)d_in[10];
    const float* blin = (const float*)d_in[11];
    float* out = (float*)d_out;

    if (ws_size >= WS_FLOATS * sizeof(float)) {
        float* w = (float*)d_ws;
        prep_kernel<<<1, 256, 0, stream>>>(Wz, bz, Wh, bh, Wlin, blin, w);
        gcn_main<<<N_GRAPHS, NPG, 0, stream>>>(x, w, out);
    } else {
        gcn_main_lds<<<N_GRAPHS, NPG, 0, stream>>>(x, Wz, bz, Wh, bh, Wlin, blin, out);
    }
}

// Round 2
// 173.522 us; speedup vs baseline: 1.0279x; 1.0279x over previous
//
#include <hip/hip_runtime.h>

// Problem constants (from reference)
#define N_GRAPHS  4096
#define NPG       256      // nodes per graph (contiguous batch segments)
#define F_IN      16
#define HID       32
#define LOG2E     1.4426950408889634f

// d_ws float layout:
//  [0..255]   : frag Z — 64 lanes x 16B f16, mfma_f32_32x32x16_f16 B layout,
//               lane l: col=l&31, k=(l>>5)*8+j. Pre-scaled by log2e.
//  [256..511] : frag H — same layout, pre-scaled by 2*log2e (raw exp2 use).
//  [512..543] : bz * log2e
//  [544..575] : bh * 2*log2e
//  [576..607] : W_lin
//  [608]      : b_lin
#define WS_FLOATS 609

typedef _Float16 half8  __attribute__((ext_vector_type(8)));   // 4 VGPR MFMA A/B
typedef float    f32x16 __attribute__((ext_vector_type(16)));  // MFMA C/D 32x32

#if __has_builtin(__builtin_amdgcn_exp2f)
#define EXP2(x) __builtin_amdgcn_exp2f(x)
#else
#define EXP2(x) exp2f(x)
#endif

union FragU { uint4 u; half8 h; };

// B fragment for lane l of frag f. W element [r][c] at r*32+c; second
// diffusion-direction copy at +1536 (W is (2,1,48,32), K=1 => sum both).
// NOTE: A is packed with the SAME lane->k map, so the contraction pairs
// x[k] with W[k] regardless of the true within-lane k order (layout-robust).
__device__ __forceinline__ uint4 make_frag32(int f, int l,
    const float* __restrict__ Wz, const float* __restrict__ Wh)
{
    const int col = l & 31, p = l >> 5;
    const float s = (f == 0) ? LOG2E : 2.0f * LOG2E;
    const float* W = (f == 0) ? Wz : Wh;
    FragU u;
#pragma unroll
    for (int j = 0; j < 8; ++j) {
        const int k = p * 8 + j;
        u.h[j] = (_Float16)((W[k * 32 + col] + W[1536 + k * 32 + col]) * s);
    }
    return u.u;
}

__global__ __launch_bounds__(256) void prep_kernel(
    const float* __restrict__ Wz, const float* __restrict__ bz,
    const float* __restrict__ Wh, const float* __restrict__ bh,
    const float* __restrict__ Wlin, const float* __restrict__ blin,
    float* __restrict__ w)
{
    const int t = threadIdx.x;                       // 256 threads, 1 block
    if (t < 128) ((uint4*)w)[t] = make_frag32(t >> 6, t & 63, Wz, Wh);
    if (t < HID) {
        w[512 + t] = bz[t] * LOG2E;
        w[544 + t] = bh[t] * (2.0f * LOG2E);
        w[576 + t] = Wlin[t];
    }
    if (t == 0) w[608] = blin[0];
}

// One (node, col) activation: omz*tanh merged into a single rcp.
// v = (e2-1) / ((1+e1)*(e2+1)); clamp keeps e2 finite (avoids inf*0 NaN).
__device__ __forceinline__ float gate_term(float az, float ah, float wl, float osum)
{
    const float e1 = EXP2(az);
    const float e2 = EXP2(fminf(ah, 126.0f));
    const float r  = __builtin_amdgcn_rcpf((1.0f + e1) * (e2 + 1.0f));
    float v = (e2 - 1.0f) * r;
    v = v > 0.0f ? v : 0.0f;                 // relu (omz>0, sign is tanh's)
    return fmaf(v, wl, osum);
}

// One 32-node tile: hi/lo f32->f16 split via two chained MFMAs per gate.
// A layout: lane l holds node (tile + (l&31)), features (l>>5)*8 .. +8 —
// 64 lanes x 8 = exactly 32 nodes x 16 features, zero duplication.
// C/D layout (HW-verified): col = lane&31, rows bijective over 0..31.
__device__ __forceinline__ float tile32(float4 c0, float4 c1,
    half8 Bz, half8 Bh, float bzl, float bhl, float wll, float osum)
{
    const float xf[8] = { c0.x, c0.y, c0.z, c0.w, c1.x, c1.y, c1.z, c1.w };
    half8 Ah, Al;
#pragma unroll
    for (int j = 0; j < 8; ++j) {
        const _Float16 h = (_Float16)xf[j];            // hi
        Ah[j] = h;
        Al[j] = (_Float16)(xf[j] - (float)h);          // exact residual
    }
    f32x16 accZ, accH;
#pragma unroll
    for (int i = 0; i < 16; ++i) { accZ[i] = bzl; accH[i] = bhl; }
    accZ = __builtin_amdgcn_mfma_f32_32x32x16_f16(Ah, Bz, accZ, 0, 0, 0);
    accH = __builtin_amdgcn_mfma_f32_32x32x16_f16(Ah, Bh, accH, 0, 0, 0);
    accZ = __builtin_amdgcn_mfma_f32_32x32x16_f16(Al, Bz, accZ, 0, 0, 0);
    accH = __builtin_amdgcn_mfma_f32_32x32x16_f16(Al, Bh, accH, 0, 0, 0);
#pragma unroll
    for (int i = 0; i < 16; ++i)
        osum = gate_term(accZ[i], accH[i], wll, osum);
    return osum;
}

// One wave = one whole graph (8 tiles of 32 nodes), software-pipelined:
// tile t+1's loads are issued BEFORE tile t's MFMA+gate phase, so the
// ~500-900 cyc memory latency is covered by ~700 cyc of compute instead of
// relying on cross-wave occupancy. No LDS, no __syncthreads.
__device__ __forceinline__ void gcn_wave(const float* __restrict__ x,
                                         const float* __restrict__ w,
                                         float* __restrict__ out, int g, int lane)
{
    const int col = lane & 31, p = lane >> 5;

    // B fragments: 2 coalesced 16B loads, already packed. L2-hot after the
    // first blocks (same 2.4 KB for every wave).
    const uint4* bq = (const uint4*)w;
    FragU uz, uh;
    uz.u = bq[lane];
    uh.u = bq[64 + lane];

    const float bzl = w[512 + col];
    const float bhl = w[544 + col];
    const float wll = w[576 + col];

    // Lane (p,col) covers features p*8..+8 of node tile*32 + col.
    const float* xw = x + ((size_t)g * NPG + col) * F_IN + p * 8;
    float4 c0 = *(const float4*)(xw);
    float4 c1 = *(const float4*)(xw + 4);
    float osum = 0.0f;

#pragma unroll
    for (int t = 0; t < 8; ++t) {
        float4 n0 = c0, n1 = c1;
        if (t < 7) {                                  // prefetch next 32-node tile
            n0 = *(const float4*)(xw + (t + 1) * 512);
            n1 = *(const float4*)(xw + (t + 1) * 512 + 4);
        }
        osum = tile32(c0, c1, uz.h, uh.h, bzl, bhl, wll, osum);
        c0 = n0; c1 = n1;
    }

    // Wave-local butterfly; lane 0 owns the graph's output. No cross-wave part.
#pragma unroll
    for (int off = 32; off > 0; off >>= 1)
        osum += __shfl_down(osum, off, 64);
    if (lane == 0)
        out[g] = osum * (1.0f / (float)NPG) + w[608];
}

// 4 graphs per block (one per wave), grid = N_GRAPHS/4.
__global__ __launch_bounds__(256, 4) void gcn_main(
    const float* __restrict__ x, const float* __restrict__ w, float* __restrict__ out)
{
    gcn_wave(x, w, out, blockIdx.x * 4 + (threadIdx.x >> 6), threadIdx.x & 63);
}

// Fallback if ws_size too small: build the same 609-float image in LDS.
__global__ __launch_bounds__(256, 4) void gcn_main_lds(
    const float* __restrict__ x,
    const float* __restrict__ Wz, const float* __restrict__ bz,
    const float* __restrict__ Wh, const float* __restrict__ bh,
    const float* __restrict__ Wlin, const float* __restrict__ blin,
    float* __restrict__ out)
{
    __shared__ __attribute__((aligned(16))) float w[WS_FLOATS];
    const int t = threadIdx.x;
    if (t < 128) ((uint4*)w)[t] = make_frag32(t >> 6, t & 63, Wz, Wh);
    if (t < HID) {
        w[512 + t] = bz[t] * LOG2E;
        w[544 + t] = bh[t] * (2.0f * LOG2E);
        w[576 + t] = Wlin[t];
    }
    if (t == 0) w[608] = blin[0];
    __syncthreads();
    gcn_wave(x, w, out, blockIdx.x * 4 + (t >> 6), t & 63);
}

extern "C" void kernel_launch(void* const* d_in, const int* in_sizes, int n_in,
                              void* d_out, int out_size, void* d_ws, size_t ws_size,
                              hipStream_t stream)
{
    // 0:x 1:edge_index 2:edge_weight 3:batch 4:W_z 5:b_z 6:W_r 7:b_r 8:W_h 9:b_h 10:W_lin 11:b_lin
    const float* x    = (const float*)d_in[0];
    const float* Wz   = (const float*)d_in[4];
    const float* bz   = (const float*)d_in[5];
    const float* Wh   = (const float*)d_in[8];
    const float* bh   = (const float*)d_in[9];
    const float* Wlin = (const float*)d_in[10];
    const float* blin = (const float*)d_in[11];
    float* out = (float*)d_out;

    if (ws_size >= WS_FLOATS * sizeof(float)) {
        float* w = (float*)d_ws;
        prep_kernel<<<1, 256, 0, stream>>>(Wz, bz, Wh, bh, Wlin, blin, w);
        gcn_main<<<N_GRAPHS / 4, 256, 0, stream>>>(x, w, out);
    } else {
        gcn_main_lds<<<N_GRAPHS / 4, 256, 0, stream>>>(x, Wz, bz, Wh, bh, Wlin, blin, out);
    }
}